// Round 1
// baseline (326.790 us; speedup 1.0000x reference)
//
#include <hip/hip_runtime.h>
#include <hip/hip_bf16.h>
#include <hip/hip_cooperative_groups.h>

namespace cg = cooperative_groups;

// Problem constants
#define NN 384
#define CUTOFF2 144.0f
#define GAMMA 1.7777778f   // (16/12)^2

// packed B-frag layout per layer (u32 units): [W1b 8192 | We 2048 | W2 8192 | C1 8192]
#define PK_L 26624
#define PK_WE 8192
#define PK_W2 10240
#define PK_C1 18432

#define STG_F32 1152                      // 32 rows x 36 f32 per-wave stage
#define EDGE_SMEM ((PK_L + 8*STG_F32)*4)  // 143360 B -> 1 block/CU

// ws byte offsets
#define O_XA 0
#define O_XB 4608
#define O_H 9216
#define O_A 205824
#define O_AGG 402432
#define O_HBF 599040
#define O_EREC 697344      // 384*384*16
#define O_UNITS 3056640
#define O_UCNT 3075072     // 3 ints, zeroed by hipMemsetAsync
#define O_MEAN 3075136     // 3 floats
#define O_PK 3075200

typedef __bf16 bf16x8 __attribute__((ext_vector_type(8)));
typedef float f32x4 __attribute__((ext_vector_type(4)));

union ER { struct { float dx, dy, dz; unsigned j; } e; uint4 u4; };

__device__ __forceinline__ unsigned short f2bf(float f){
  unsigned u = __float_as_uint(f);
  return (unsigned short)((u + 0x7fffu + ((u >> 16) & 1u)) >> 16);  // RNE
}
__device__ __forceinline__ unsigned pk2(float a, float b){
  return ((unsigned)f2bf(b) << 16) | f2bf(a);
}
__device__ __forceinline__ float silu(float x){ return x / (1.0f + __expf(-x)); }

// ---- scan tail: radius graph -> 16B edge records {diff,j}, publish units
__device__ __forceinline__ void scan_tail(
    int row, int rowsel, int t256, bool v, const float* __restrict__ x,
    uint4* __restrict__ erec, int* __restrict__ units, int* __restrict__ ucntSlot,
    int* scn){
  int* scnt  = scn + rowsel*2;
  int* sbase = scnt + 1;
  if (t256 == 0) *scnt = 0;
  __syncthreads();
  if (v) {
    float xi0 = x[row*3], xi1 = x[row*3+1], xi2 = x[row*3+2];
    for (int j = t256; j < 384; j += 256) {
      float d0 = xi0-x[j*3], d1 = xi1-x[j*3+1], d2 = xi2-x[j*3+2];
      float dd = d0*d0 + d1*d1 + d2*d2;
      bool msk = ((dd < CUTOFF2) && (j != row)) || (j == row-1) || (j == row+1);
      if (msk) {
        int ss = atomicAdd(scnt, 1);
        ER er; er.e.dx = d0; er.e.dy = d1; er.e.dz = d2; er.e.j = (unsigned)j;
        erec[row*384 + ss] = er.u4;
      }
    }
  }
  __syncthreads();
  if (v) {
    int cnt = *scnt;
    int p = (32 - (cnt & 31)) & 31;
    if (t256 < p) {
      ER er; er.e.dx = 0.f; er.e.dy = 0.f; er.e.dz = 0.f; er.e.j = (unsigned)row;
      erec[row*384 + cnt + t256] = er.u4;
    }
    if (t256 == 0) *sbase = atomicAdd(ucntSlot, (cnt + 31) >> 5);
  }
  __syncthreads();
  if (v) {
    int cnt = *scnt, nu = (cnt + 31) >> 5;
    if (t256 < nu) {
      int nv = cnt - (t256 << 5); if (nv > 32) nv = 32;
      units[*sbase + t256] = row | (t256 << 9) | (nv << 13);
    }
  }
}

// ---- C-layout -> A-frag transpose via per-wave f32 LDS pad (wave-private, no fences)
#define TRANSFORM(VA, VB, FA, FB)                                              \
  _Pragma("unroll")                                                            \
  for (int c = 0; c < 4; ++c) {                                                \
    _Pragma("unroll")                                                          \
    for (int tl = 0; tl < 2; ++tl) {                                           \
      int t = 2*c + tl;                                                        \
      _Pragma("unroll")                                                        \
      for (int r = 0; r < 4; ++r) {                                            \
        stg[(quad*4 + r)*36 + tl*16 + col0] = VA[t][r];                        \
        stg[(16 + quad*4 + r)*36 + tl*16 + col0] = VB[t][r];                   \
      }                                                                        \
    }                                                                          \
    float4 lo = *(const float4*)(stg + col0*36 + quad*8);                      \
    float4 hi = *(const float4*)(stg + col0*36 + quad*8 + 4);                  \
    FA[c].u = make_uint4(pk2(lo.x,lo.y), pk2(lo.z,lo.w),                       \
                         pk2(hi.x,hi.y), pk2(hi.z,hi.w));                      \
    float4 lo2 = *(const float4*)(stg + (16 + col0)*36 + quad*8);              \
    float4 hi2 = *(const float4*)(stg + (16 + col0)*36 + quad*8 + 4);          \
    FB[c].u = make_uint4(pk2(lo2.x,lo2.y), pk2(lo2.z,lo2.w),                   \
                         pk2(hi2.x,hi2.y), pk2(hi2.z,hi2.w));                  \
  }

// ---- MFMA edge phase (body identical to proven k_edge, minus stage/return)
__device__ __forceinline__ void edge_phase(
    float* __restrict__ x_out, const float* __restrict__ Ag,
    const unsigned short* __restrict__ hbf, const uint4* __restrict__ erec,
    const int* __restrict__ units, const int U,
    float* __restrict__ agg, unsigned* smem,
    const float* __restrict__ eb2g, const float* __restrict__ cb1g,
    const float* __restrict__ cw2g){
  const int tid = threadIdx.x, q = tid & 63, s = tid >> 6;
  const int col0 = q & 15, quad = q >> 4;
  float eb2v[8], cb1v[8], cw2v[8];
  #pragma unroll
  for (int t = 0; t < 8; ++t) {
    int c = t*16 + col0;
    eb2v[t] = eb2g[c]; cb1v[t] = cb1g[c]; cw2v[t] = cw2g[c];
  }
  float* stg = (float*)(smem + PK_L) + s*STG_F32;
  const f32x4 z4 = {0.f, 0.f, 0.f, 0.f};
  union U8 { uint4 u; bf16x8 v; };

  for (int u = blockIdx.x + 256*s; u < U; u += 2048) {
    const int desc = units[u];
    const int i = desc & 511, b = (desc >> 9) & 15, nvalid = (desc >> 13) & 63;
    float Aval[8];
    #pragma unroll
    for (int t = 0; t < 8; ++t) Aval[t] = Ag[i*128 + t*16 + col0];
    ER e0, e1;
    e0.u4 = erec[i*384 + b*32 + col0];
    e1.u4 = erec[i*384 + b*32 + 16 + col0];
    const int j0 = (int)e0.e.j, j1 = (int)e1.e.j;
    const float d0x = e0.e.dx, d0y = e0.e.dy, d0z = e0.e.dz;
    const float d1x = e1.e.dx, d1y = e1.e.dy, d1z = e1.e.dz;
    const float dd0 = sqrtf(d0x*d0x + d0y*d0y + d0z*d0z);
    const float dd1 = sqrtf(d1x*d1x + d1y*d1y + d1z*d1z);

    U8 ha0[4], ha1[4];
    #pragma unroll
    for (int c = 0; c < 4; ++c) {
      ha0[c].u = *(const uint4*)(hbf + j0*128 + c*32 + quad*8);
      ha1[c].u = *(const uint4*)(hbf + j1*128 + c*32 + quad*8);
    }

    U8 cve0, cve1;
    if (q < 32) {
      #pragma unroll
      for (int tp = 0; tp < 4; ++tp) {
        float k0 = (float)(quad*8 + 2*tp);
        float t00 = dd0 - 0.8f*k0, t01 = dd0 - 0.8f*(k0+1.f);
        float t10 = dd1 - 0.8f*k0, t11 = dd1 - 0.8f*(k0+1.f);
        (&cve0.u.x)[tp] = pk2(__expf(-GAMMA*t00*t00), __expf(-GAMMA*t01*t01));
        (&cve1.u.x)[tp] = pk2(__expf(-GAMMA*t10*t10), __expf(-GAMMA*t11*t11));
      }
    } else { cve0.u = make_uint4(0,0,0,0); cve1.u = make_uint4(0,0,0,0); }

    // GEMM1: m1 = silu(h_j@W1b + e@We + A_i), 32 rows
    f32x4 acc0[8], acc1[8];
    #pragma unroll
    for (int t = 0; t < 8; ++t) { acc0[t] = z4; acc1[t] = z4; }
    #pragma unroll
    for (int t = 0; t < 8; ++t) {
      #pragma unroll
      for (int c = 0; c < 4; ++c) {
        bf16x8 w = *(const bf16x8*)(smem + ((t*4 + c)*64 + q)*4);
        acc0[t] = __builtin_amdgcn_mfma_f32_16x16x32_bf16(ha0[c].v, w, acc0[t], 0, 0, 0);
        acc1[t] = __builtin_amdgcn_mfma_f32_16x16x32_bf16(ha1[c].v, w, acc1[t], 0, 0, 0);
      }
      bf16x8 we = *(const bf16x8*)(smem + PK_WE + (t*64 + q)*4);
      acc0[t] = __builtin_amdgcn_mfma_f32_16x16x32_bf16(cve0.v, we, acc0[t], 0, 0, 0);
      acc1[t] = __builtin_amdgcn_mfma_f32_16x16x32_bf16(cve1.v, we, acc1[t], 0, 0, 0);
    }
    #pragma unroll
    for (int t = 0; t < 8; ++t)
      #pragma unroll
      for (int r = 0; r < 4; ++r) {
        acc0[t][r] = silu(acc0[t][r] + Aval[t]);
        acc1[t][r] = silu(acc1[t][r] + Aval[t]);
      }

    U8 a20[4], a21[4];
    TRANSFORM(acc0, acc1, a20, a21);

    // GEMM2: m = silu(m1@eW2 + eb2)
    f32x4 m0[8], m1v[8];
    #pragma unroll
    for (int t = 0; t < 8; ++t) { m0[t] = z4; m1v[t] = z4; }
    #pragma unroll
    for (int t = 0; t < 8; ++t)
      #pragma unroll
      for (int c = 0; c < 4; ++c) {
        bf16x8 w = *(const bf16x8*)(smem + PK_W2 + ((t*4 + c)*64 + q)*4);
        m0[t] = __builtin_amdgcn_mfma_f32_16x16x32_bf16(a20[c].v, w, m0[t], 0, 0, 0);
        m1v[t] = __builtin_amdgcn_mfma_f32_16x16x32_bf16(a21[c].v, w, m1v[t], 0, 0, 0);
      }
    #pragma unroll
    for (int t = 0; t < 8; ++t) {
      float cs = 0.f;
      #pragma unroll
      for (int r = 0; r < 4; ++r) {
        m0[t][r] = silu(m0[t][r] + eb2v[t]);
        m1v[t][r] = silu(m1v[t][r] + eb2v[t]);
        if (quad*4 + r < nvalid) cs += m0[t][r];
        if (16 + quad*4 + r < nvalid) cs += m1v[t][r];
      }
      cs += __shfl_xor(cs, 16); cs += __shfl_xor(cs, 32);
      if (q < 16) atomicAdd(&agg[i*128 + t*16 + q], cs);
    }

    U8 a30[4], a31[4];
    TRANSFORM(m0, m1v, a30, a31);

    // GEMM3: c1 = silu(m@cW1 + cb1); w_row = c1 . cW2
    f32x4 c30[8], c31[8];
    #pragma unroll
    for (int t = 0; t < 8; ++t) { c30[t] = z4; c31[t] = z4; }
    #pragma unroll
    for (int t = 0; t < 8; ++t)
      #pragma unroll
      for (int c = 0; c < 4; ++c) {
        bf16x8 w = *(const bf16x8*)(smem + PK_C1 + ((t*4 + c)*64 + q)*4);
        c30[t] = __builtin_amdgcn_mfma_f32_16x16x32_bf16(a30[c].v, w, c30[t], 0, 0, 0);
        c31[t] = __builtin_amdgcn_mfma_f32_16x16x32_bf16(a31[c].v, w, c31[t], 0, 0, 0);
      }
    float p0[4], p1[4];
    #pragma unroll
    for (int r = 0; r < 4; ++r) {
      float pa = 0.f, pb = 0.f;
      #pragma unroll
      for (int t = 0; t < 8; ++t) {
        pa += silu(c30[t][r] + cb1v[t]) * cw2v[t];
        pb += silu(c31[t][r] + cb1v[t]) * cw2v[t];
      }
      if (quad*4 + r >= nvalid) pa = 0.f;
      if (16 + quad*4 + r >= nvalid) pb = 0.f;
      p0[r] = pa; p1[r] = pb;
    }
    #pragma unroll
    for (int r = 0; r < 4; ++r)
      #pragma unroll
      for (int off = 1; off < 16; off <<= 1) {
        p0[r] += __shfl_xor(p0[r], off);
        p1[r] += __shfl_xor(p1[r], off);
      }
    float dx0 = 0.f, dx1 = 0.f, dx2 = 0.f;
    #pragma unroll
    for (int r = 0; r < 4; ++r) {
      int el = quad*4 + r;
      float s0 = __shfl(d0x, el), s1 = __shfl(d0y, el), s2 = __shfl(d0z, el);
      if (col0 == 0) { dx0 += p0[r]*s0; dx1 += p0[r]*s1; dx2 += p0[r]*s2; }
      float u0 = __shfl(d1x, el), u1 = __shfl(d1y, el), u2 = __shfl(d1z, el);
      if (col0 == 0) { dx0 += p1[r]*u0; dx1 += p1[r]*u1; dx2 += p1[r]*u2; }
    }
    dx0 += __shfl_xor(dx0, 16); dx0 += __shfl_xor(dx0, 32);
    dx1 += __shfl_xor(dx1, 16); dx1 += __shfl_xor(dx1, 32);
    dx2 += __shfl_xor(dx2, 16); dx2 += __shfl_xor(dx2, 32);
    if (q == 0) {
      atomicAdd(&x_out[i*3 + 0], dx0);
      atomicAdd(&x_out[i*3 + 1], dx1);
      atomicAdd(&x_out[i*3 + 2], dx2);
    }
  }
}

// ---- node phase (body identical to proven k_node incl. trailing scan)
__device__ __forceinline__ void node_phase(
    const float* __restrict__ nW1l, const float* __restrict__ nb1l,
    const float* __restrict__ nW2l, const float* __restrict__ nb2l,
    const float* __restrict__ eW1n, const float* __restrict__ eb1n,
    float* __restrict__ h, unsigned short* __restrict__ hbf,
    float* __restrict__ agg, float* __restrict__ A,
    const float* __restrict__ xsrc, float* __restrict__ xdst,
    const float* __restrict__ meanp,
    uint4* __restrict__ erec, int* __restrict__ units, int* __restrict__ ucntSlot,
    float* sb2f, int* scn){
  const int tid = threadIdx.x;
  const int rowsel = tid >> 8, half = (tid >> 7) & 1, o = tid & 127, t256 = tid & 255;
  const int row = blockIdx.x + 256*rowsel;
  const bool v = row < NN;
  float* sb = sb2f + rowsel*768;
  float* sh = sb; float* sg = sb+128; float* st = sb+256; float* shn = sb+384; float* part = sb+512;

  if (v) {
    if (half == 0) {
      sh[o] = h[row*128 + o];
      if (o < 3) {
        float m = meanp ? meanp[o] : 0.f;
        xdst[row*3 + o] = xsrc[row*3 + o] - m;
      }
    } else {
      sg[o] = agg[row*128 + o]; agg[row*128 + o] = 0.f;
    }
  }
  __syncthreads();
  float aa = 0.f;
  if (v) {
    const float* src = half ? sg : sh;
    const float* wb  = nW1l + half*128*128;
    float a0=0,a1=0,a2=0,a3=0;
    #pragma unroll 16
    for (int k = 0; k < 128; k += 4) {
      a0 += src[k]   * wb[k*128 + o];
      a1 += src[k+1] * wb[(k+1)*128 + o];
      a2 += src[k+2] * wb[(k+2)*128 + o];
      a3 += src[k+3] * wb[(k+3)*128 + o];
    }
    aa = (a0+a1)+(a2+a3);
    if (half) part[o] = aa;
  }
  __syncthreads();
  if (v && !half) st[o] = silu(nb1l[o] + aa + part[o]);
  __syncthreads();
  float bb = 0.f;
  if (v) {
    int k0 = half*64;
    float b0=0,b1=0,b2=0,b3=0;
    #pragma unroll 16
    for (int k = k0; k < k0+64; k += 4) {
      b0 += st[k]   * nW2l[k*128 + o];
      b1 += st[k+1] * nW2l[(k+1)*128 + o];
      b2 += st[k+2] * nW2l[(k+2)*128 + o];
      b3 += st[k+3] * nW2l[(k+3)*128 + o];
    }
    bb = (b0+b1)+(b2+b3);
    if (half) part[o] = bb;
  }
  __syncthreads();
  if (v && !half) {
    float hn = sh[o] + nb2l[o] + bb + part[o];
    h[row*128 + o] = hn; shn[o] = hn;
    hbf[row*128 + o] = f2bf(hn);
  }
  __syncthreads();
  float cc = 0.f;
  if (v) {
    int k0 = half*64;
    float c0=0,c1=0,c2=0,c3=0;
    #pragma unroll 16
    for (int k = k0; k < k0+64; k += 4) {
      c0 += shn[k]   * eW1n[k*128 + o];
      c1 += shn[k+1] * eW1n[(k+1)*128 + o];
      c2 += shn[k+2] * eW1n[(k+2)*128 + o];
      c3 += shn[k+3] * eW1n[(k+3)*128 + o];
    }
    cc = (c0+c1)+(c2+c3);
    if (half) part[o] = cc;
  }
  __syncthreads();
  if (v && !half) A[row*128 + o] = eb1n[o] + cc + part[o];

  scan_tail(row, rowsel, t256, v, xsrc, erec, units, ucntSlot, scn);
}

// ---- fused cooperative kernel: init | [stage+edge | node+scan] x3
__global__ __launch_bounds__(512, 1) void k_fused(
    const float* __restrict__ z, const float* __restrict__ anchor,
    const float* __restrict__ projW, const float* __restrict__ projb,
    const float* __restrict__ eW1, const float* __restrict__ eb1,
    const float* __restrict__ eW2, const float* __restrict__ eb2,
    const float* __restrict__ nW1, const float* __restrict__ nb1,
    const float* __restrict__ nW2, const float* __restrict__ nb2,
    const float* __restrict__ cW1, const float* __restrict__ cb1,
    const float* __restrict__ cW2,
    float* __restrict__ out,
    float* __restrict__ xA, float* __restrict__ xB,
    float* __restrict__ h, unsigned short* __restrict__ hbf,
    float* __restrict__ A, float* __restrict__ agg,
    uint4* __restrict__ erec, int* __restrict__ units, int* __restrict__ ucnt,
    float* __restrict__ meanw, unsigned* __restrict__ pk){
  cg::grid_group grid = cg::this_grid();
  extern __shared__ unsigned smem[];
  const int b = blockIdx.x, tid = threadIdx.x;
  const int rowsel = tid >> 8, half = (tid >> 7) & 1, o = tid & 127, t256 = tid & 255;
  float* sb2f = (float*)(smem + PK_L);   // 1536 f32 node/proj scratch (reused by edge stg)
  int* scn = (int*)(sb2f + 1536);        // 4 ints scan scratch

  // ---------- Phase A: pack + mean + proj/seed + scan L0 (ucnt pre-zeroed by memset)
  {
    int t = b*512 + tid;                 // 131072 slots cover 3*PK_L = 79872 pack elems
    if (t < 3*PK_L) {
      int layer = t / PK_L, r = t % PK_L;
      const float* src; int fr; int isWe = 0;
      if (r < PK_WE)        { fr = r;          src = eW1 + (layer*272 + 128)*128; }
      else if (r < PK_W2)   { fr = r - PK_WE;  src = eW1 + (layer*272 + 256)*128; isWe = 1; }
      else if (r < PK_C1)   { fr = r - PK_W2;  src = eW2 + layer*128*128; }
      else                  { fr = r - PK_C1;  src = cW1 + layer*128*128; }
      int tp = fr & 3, ll = (fr >> 2) & 63, nc = fr >> 8;
      int n, k;
      if (!isWe) { n = nc >> 2; int c = nc & 3; k = c*32 + ((ll>>4)<<3) + 2*tp; }
      else       { n = nc;                      k = ((ll>>4)<<3) + 2*tp; }
      int nn2 = n*16 + (ll & 15);
      float w0, w1;
      if (isWe) { w0 = (k < 16)   ? src[k*128+nn2]     : 0.f;
                  w1 = (k+1 < 16) ? src[(k+1)*128+nn2] : 0.f; }
      else      { w0 = src[k*128+nn2]; w1 = src[(k+1)*128+nn2]; }
      pk[t] = ((unsigned)f2bf(w1) << 16) | f2bf(w0);
    }
  }
  if (b == 0) {                          // mean of anchors (block 0 does no proj)
    float* ssum = sb2f;
    if (tid < 3) ssum[tid] = 0.f;
    __syncthreads();
    if (tid < 384) {
      atomicAdd(&ssum[0], anchor[tid*3]);
      atomicAdd(&ssum[1], anchor[tid*3+1]);
      atomicAdd(&ssum[2], anchor[tid*3+2]);
    }
    __syncthreads();
    if (tid < 3) meanw[tid] = ssum[tid]*(1.f/384.f);
  }
  if (b >= 64) {                         // proj + A-precompute + seeds, 2 rows/block
    const int row = (b - 64)*2 + rowsel;
    float* sb = sb2f + rowsel*768;
    float* sh = sb; float* part = sb + 512; float* sz = sb + 640;
    if (half == 0) { if (o < 64) sz[o] = z[row*64 + o]; }
    else           agg[row*128 + o] = 0.f;
    if (half == 0 && o < 3) xB[row*3 + o] = anchor[row*3 + o];
    __syncthreads();
    float pp = 0.f;
    {
      int k0 = half*32;
      float p0=0,p1=0,p2=0,p3=0;
      #pragma unroll 8
      for (int k = k0; k < k0+32; k += 4) {
        p0 += sz[k]   * projW[k*128 + o];
        p1 += sz[k+1] * projW[(k+1)*128 + o];
        p2 += sz[k+2] * projW[(k+2)*128 + o];
        p3 += sz[k+3] * projW[(k+3)*128 + o];
      }
      pp = (p0+p1)+(p2+p3);
      if (half) part[o] = pp;
    }
    __syncthreads();
    if (!half) {
      float hh = projb[o] + pp + part[o];
      h[row*128 + o] = hh; sh[o] = hh;
      hbf[row*128 + o] = f2bf(hh);
    }
    __syncthreads();
    float cc = 0.f;
    {
      int k0 = half*64;
      float c0=0,c1=0,c2=0,c3=0;
      #pragma unroll 16
      for (int k = k0; k < k0+64; k += 4) {
        c0 += sh[k]   * eW1[k*128 + o];
        c1 += sh[k+1] * eW1[(k+1)*128 + o];
        c2 += sh[k+2] * eW1[(k+2)*128 + o];
        c3 += sh[k+3] * eW1[(k+3)*128 + o];
      }
      cc = (c0+c1)+(c2+c3);
      if (half) part[o] = cc;
    }
    __syncthreads();
    if (!half) A[row*128 + o] = eb1[o] + cc + part[o];
  }
  // scan L0 on raw anchors (mean-free), 2 rows/block for b<192
  scan_tail(b*2 + rowsel, rowsel, t256, b < 192, anchor, erec, units, ucnt, scn);

  // ---------- 3 layers: [sync | stage+edge] + [sync | node+scan]
  for (int l = 0; l < 3; ++l) {
    grid.sync();                         // pack/scan(l) complete grid-wide
    for (int idx = tid; idx < PK_L/4; idx += 512)
      ((uint4*)smem)[idx] = ((const uint4*)(pk + l*PK_L))[idx];
    __syncthreads();
    const int U = ((volatile const int*)ucnt)[l];
    float* x_out = (l == 0) ? xB : ((l == 1) ? xA : out);
    edge_phase(x_out, A, hbf, erec, units, U, agg, smem,
               eb2 + l*128, cb1 + l*128, cW2 + l*128);
    if (l == 2) break;
    grid.sync();                         // edge(l) atomics complete grid-wide
    node_phase(nW1 + l*256*128, nb1 + l*128, nW2 + l*128*128, nb2 + l*128,
               eW1 + (l+1)*272*128, eb1 + (l+1)*128,
               h, hbf, agg, A,
               (l == 0) ? xB : xA, (l == 0) ? xA : out,
               (l == 0) ? (const float*)nullptr : meanw,
               erec, units, ucnt + (l+1), sb2f, scn);
  }
}

extern "C" void kernel_launch(void* const* d_in, const int* in_sizes, int n_in,
                              void* d_out, int out_size, void* d_ws, size_t ws_size,
                              hipStream_t stream){
  const float* z      = (const float*)d_in[0];
  const float* anchor = (const float*)d_in[1];
  const float* projW  = (const float*)d_in[2];
  const float* projb  = (const float*)d_in[3];
  const float* eW1    = (const float*)d_in[4];
  const float* eb1    = (const float*)d_in[5];
  const float* eW2    = (const float*)d_in[6];
  const float* eb2    = (const float*)d_in[7];
  const float* nW1    = (const float*)d_in[8];
  const float* nb1    = (const float*)d_in[9];
  const float* nW2    = (const float*)d_in[10];
  const float* nb2    = (const float*)d_in[11];
  const float* cW1    = (const float*)d_in[12];
  const float* cb1    = (const float*)d_in[13];
  const float* cW2    = (const float*)d_in[14];
  float* out = (float*)d_out;

  char* w = (char*)d_ws;
  float* xA  = (float*)(w + O_XA);
  float* xB  = (float*)(w + O_XB);
  float* h   = (float*)(w + O_H);
  float* A   = (float*)(w + O_A);
  float* agg = (float*)(w + O_AGG);
  unsigned short* hbf = (unsigned short*)(w + O_HBF);
  uint4* erec = (uint4*)(w + O_EREC);
  int* units = (int*)(w + O_UNITS);
  int* ucnt  = (int*)(w + O_UCNT);
  float* meanw = (float*)(w + O_MEAN);
  unsigned* pk = (unsigned*)(w + O_PK);

  hipFuncSetAttribute((const void*)k_fused, hipFuncAttributeMaxDynamicSharedMemorySize, EDGE_SMEM);

  hipMemsetAsync(ucnt, 0, 12, stream);
  void* args[] = { &z, &anchor, &projW, &projb, &eW1, &eb1, &eW2, &eb2,
                   &nW1, &nb1, &nW2, &nb2, &cW1, &cb1, &cW2, &out,
                   &xA, &xB, &h, &hbf, &A, &agg, &erec, &units, &ucnt, &meanw, &pk };
  hipLaunchCooperativeKernel((const void*)k_fused, dim3(256), dim3(512),
                             args, EDGE_SMEM, stream);
}